// Round 15
// baseline (2703.136 us; speedup 1.0000x reference)
//
#include <hip/hip_runtime.h>
#include <math.h>

#define B 16
#define S 256
#define H 768
#define NH 12
#define DH 64
#define DFF 3072
#define L 12
#define T 9
#define M (B*S)
#define LN_EPS 1e-12f
#define QKVS (3*H)
#define NCH 16   // CRF chunks per batch
#define MH ((size_t)M * H)

typedef __attribute__((ext_vector_type(8))) __bf16 bf16x8;
typedef __attribute__((ext_vector_type(8))) unsigned short u16x8;
typedef __attribute__((ext_vector_type(4))) unsigned short u16x4;
typedef __attribute__((ext_vector_type(4))) float f32x4;
typedef __attribute__((ext_vector_type(4))) unsigned char u8x4;

__device__ __forceinline__ unsigned short f2bf(float f) {
    unsigned int u = __float_as_uint(f);
    unsigned int r = u + 0x7fffu + ((u >> 16) & 1u);
    return (unsigned short)(r >> 16);
}
__device__ __forceinline__ float bf2f(unsigned short h) {
    return __uint_as_float((unsigned int)h << 16);
}
// f32 -> OCP e4m3fn (RNE, clamp 448, subnormal step 2^-9)
__device__ __forceinline__ unsigned char f2e4m3(float f) {
    unsigned int u = __float_as_uint(f);
    unsigned char s = (unsigned char)((u >> 24) & 0x80);
    unsigned int a = u & 0x7FFFFFFFu;
    if (a >= 0x43E00000u) return s | 0x7E;          // >= 448 -> max finite
    if (a < 0x3C800000u) {                           // < 2^-6 -> subnormal units of 2^-9
        int q = (int)(__uint_as_float(a) * 512.0f + 0.5f);
        if (q > 8) q = 8;
        return s | (unsigned char)q;                 // q==8 encodes 2^-6 exactly
    }
    unsigned int r = a + 0x7FFFFu + ((a >> 20) & 1u);
    if (r >= 0x43E80000u) return s | 0x7E;
    int e = (int)(r >> 23) - 127;
    return s | (unsigned char)(((e + 7) << 3) | ((r >> 20) & 7));
}

#define WSCL 64.0f
#define WINV 0.015625f   // 1/64

// ---------------- Merged weight convert+transpose (4 HxH weights) -> fp8 x64 ----------------
__global__ void convT4_kernel(const float* __restrict__ Wq, const float* __restrict__ Wk,
                              const float* __restrict__ Wv, const float* __restrict__ Wo,
                              unsigned char* __restrict__ wqkv8, unsigned char* __restrict__ wo8) {
    __shared__ float tile[32][33];
    const int z = blockIdx.z;
    const int which = z / L, layer = z - which * L;
    const float* Wp = (which == 0 ? Wq : which == 1 ? Wk : which == 2 ? Wv : Wo)
                      + (size_t)layer * H * H;
    unsigned char* Tp = (which < 3)
        ? wqkv8 + (size_t)layer * 3 * H * H + (size_t)which * H * H
        : wo8 + (size_t)layer * H * H;
    const int n0 = blockIdx.x * 32, k0 = blockIdx.y * 32;
    const int tx = threadIdx.x, ty = threadIdx.y;  // 32 x 8
#pragma unroll
    for (int i = 0; i < 32; i += 8)
        tile[ty + i][tx] = Wp[(size_t)(k0 + ty + i) * H + n0 + tx];
    __syncthreads();
    {
        const int u = ty * 32 + tx;
        const int r = u >> 3, kq = (u & 7) << 2;
        u8x4 o;
#pragma unroll
        for (int j = 0; j < 4; ++j) o[j] = f2e4m3(tile[kq + j][r] * WSCL);
        *(u8x4*)&Tp[(size_t)(n0 + r) * H + k0 + kq] = o;
    }
}

// ---------------- Weight convert+transpose (generic) -> fp8 x64 ----------------
__global__ void convT_kernel(const float* __restrict__ W, unsigned char* __restrict__ W8,
                             int K, int N, size_t dstLayerStride) {
    __shared__ float tile[32][33];
    const int layer = blockIdx.z;
    const float* Wp = W + (size_t)layer * K * N;
    unsigned char* Tp = W8 + (size_t)layer * dstLayerStride;
    const int n0 = blockIdx.x * 32, k0 = blockIdx.y * 32;
    const int tx = threadIdx.x, ty = threadIdx.y;
#pragma unroll
    for (int i = 0; i < 32; i += 8)
        tile[ty + i][tx] = Wp[(size_t)(k0 + ty + i) * N + n0 + tx];
    __syncthreads();
    {
        const int u = ty * 32 + tx;
        const int r = u >> 3, kq = (u & 7) << 2;
        u8x4 o;
#pragma unroll
        for (int j = 0; j < 4; ++j) o[j] = f2e4m3(tile[kq + j][r] * WSCL);
        *(u8x4*)&Tp[(size_t)(n0 + r) * K + k0 + kq] = o;
    }
}

// ---------------- Concat QKV biases per layer: [L][2304] ----------------
__global__ void biascat_kernel(const float* __restrict__ bq, const float* __restrict__ bk,
                               const float* __restrict__ bv, float* __restrict__ out) {
    int idx = blockIdx.x * 256 + threadIdx.x;
    if (idx >= L * QKVS) return;
    int l = idx / QKVS, c = idx % QKVS;
    float v = (c < H) ? bq[l * H + c] : (c < 2 * H) ? bk[l * H + c - H] : bv[l * H + c - 2 * H];
    out[idx] = v;
}

// ---------------- Embedding + LayerNorm (bf16 stream + fp8 GEMM-operand copy) ----------------
__global__ void embed_ln_kernel(const int* __restrict__ x,
                                const float* __restrict__ word_emb,
                                const float* __restrict__ pos_emb,
                                const float* __restrict__ type_emb,
                                const float* __restrict__ g,
                                const float* __restrict__ bta,
                                unsigned short* __restrict__ hb,
                                unsigned char* __restrict__ hb8) {
    const int row = blockIdx.x;
    const int s = row % S;
    const int tok = x[row];
    const int t = threadIdx.x;     // 192
    const int c = t << 2;
    const float4 wv = *(const float4*)&word_emb[(size_t)tok * H + c];
    const float4 pv = *(const float4*)&pos_emb[s * H + c];
    const float4 tv = *(const float4*)&type_emb[c];
    float v[4] = {wv.x + pv.x + tv.x, wv.y + pv.y + tv.y, wv.z + pv.z + tv.z, wv.w + pv.w + tv.w};
    float s1 = v[0] + v[1] + v[2] + v[3];
    float s2 = v[0]*v[0] + v[1]*v[1] + v[2]*v[2] + v[3]*v[3];
#pragma unroll
    for (int o = 32; o; o >>= 1) { s1 += __shfl_xor(s1, o); s2 += __shfl_xor(s2, o); }
    __shared__ float ws[3][2];
    const int w = t >> 6, l = t & 63;
    if (l == 0) { ws[w][0] = s1; ws[w][1] = s2; }
    __syncthreads();
    const float S1 = ws[0][0] + ws[1][0] + ws[2][0];
    const float S2 = ws[0][1] + ws[1][1] + ws[2][1];
    const float mean = S1 * (1.0f / H);
    const float var = fmaxf(S2 * (1.0f / H) - mean * mean, 0.f);
    const float inv = rsqrtf(var + LN_EPS);
    const float4 gv = *(const float4*)&g[c];
    const float4 bv = *(const float4*)&bta[c];
    float o0 = (v[0] - mean) * inv * gv.x + bv.x;
    float o1 = (v[1] - mean) * inv * gv.y + bv.y;
    float o2 = (v[2] - mean) * inv * gv.z + bv.z;
    float o3 = (v[3] - mean) * inv * gv.w + bv.w;
    u16x4 ob = {f2bf(o0), f2bf(o1), f2bf(o2), f2bf(o3)};
    *(u16x4*)&hb[(size_t)row * H + c] = ob;
    u8x4 o8 = {f2e4m3(o0), f2e4m3(o1), f2e4m3(o2), f2e4m3(o3)};
    *(u8x4*)&hb8[(size_t)row * H + c] = o8;
}

// ---------------- Residual + LayerNorm (bf16 stream, fp8 copy; sums NS delta partials) ----------------
template<int NS>
__global__ void residual_ln_kernel(unsigned short* __restrict__ hb,
                                   unsigned char* __restrict__ hb8,
                                   const unsigned short* __restrict__ delta,
                                   const float* __restrict__ g,
                                   const float* __restrict__ bta) {
    const int row = blockIdx.x;
    const int t = threadIdx.x;     // 192
    const int c = t << 2;
    const size_t base = (size_t)row * H + c;
    const u16x4 hv4 = *(const u16x4*)&hb[base];
    float v[4] = {bf2f(hv4[0]), bf2f(hv4[1]), bf2f(hv4[2]), bf2f(hv4[3])};
#pragma unroll
    for (int sgm = 0; sgm < NS; ++sgm) {
        const u16x4 dv4 = *(const u16x4*)&delta[sgm * MH + base];
#pragma unroll
        for (int j = 0; j < 4; ++j) v[j] += bf2f(dv4[j]);
    }
    float s1 = v[0] + v[1] + v[2] + v[3];
    float s2 = v[0]*v[0] + v[1]*v[1] + v[2]*v[2] + v[3]*v[3];
#pragma unroll
    for (int o = 32; o; o >>= 1) { s1 += __shfl_xor(s1, o); s2 += __shfl_xor(s2, o); }
    __shared__ float ws[3][2];
    const int w = t >> 6, l = t & 63;
    if (l == 0) { ws[w][0] = s1; ws[w][1] = s2; }
    __syncthreads();
    const float S1 = ws[0][0] + ws[1][0] + ws[2][0];
    const float S2 = ws[0][1] + ws[1][1] + ws[2][1];
    const float mean = S1 * (1.0f / H);
    const float var = fmaxf(S2 * (1.0f / H) - mean * mean, 0.f);
    const float inv = rsqrtf(var + LN_EPS);
    const float4 gv = *(const float4*)&g[c];
    const float4 bv = *(const float4*)&bta[c];
    float o0 = (v[0] - mean) * inv * gv.x + bv.x;
    float o1 = (v[1] - mean) * inv * gv.y + bv.y;
    float o2 = (v[2] - mean) * inv * gv.z + bv.z;
    float o3 = (v[3] - mean) * inv * gv.w + bv.w;
    u16x4 ob = {f2bf(o0), f2bf(o1), f2bf(o2), f2bf(o3)};
    *(u16x4*)&hb[base] = ob;
    u8x4 o8 = {f2e4m3(o0), f2e4m3(o1), f2e4m3(o2), f2e4m3(o3)};
    *(u8x4*)&hb8[base] = o8;
}

#define LSTR8 80   // bytes per LDS row (64 data + 16 pad): conflict-free b64 reads / b128 writes

// ---------------- fp8 MFMA GEMM: C = (A8 . W8^T)/64 (+ bias on split 0) ----------------
// Tile (MR*32) x (NR*32), 4 waves (2x2). Reg-staged LDS, BK=64 (bytes), 3 blocks/CU.
// K-split via blockIdx.z; XCD swizzle on (x,y). OUT8: write fp8 (for next GEMM's A), else bf16.
template<int ACT, int MR, int NR, int OUT8>
__global__ __launch_bounds__(256, 3)
void gemm_fp8(const unsigned char* __restrict__ A,
              const unsigned char* __restrict__ W8,
              const float* __restrict__ bias,
              unsigned short* __restrict__ Cb,
              unsigned char* __restrict__ C8,
              int Ksub, int Kfull, int N, size_t splitStride) {
    __shared__ unsigned char lA[MR * 32 * LSTR8];
    __shared__ unsigned char lB[NR * 32 * LSTR8];
    const int tid = threadIdx.x;
    const int z = blockIdx.z;
    const int gx = gridDim.x;
    const int nb = gx * gridDim.y;
    int f = blockIdx.y * gx + blockIdx.x;
    f = (f & 7) * (nb >> 3) + (f >> 3);
    const int m0 = (f / gx) * (MR * 32), n0 = (f % gx) * (NR * 32);
    const int l = tid & 63, w = tid >> 6;
    const int wr = w >> 1, wc = w & 1;
    const int lr = l & 15, kg = l >> 4;

    // staging: thread covers 16 bytes at (row = p*64 + tid>>2, col = (tid&3)*16)
    const int srow = tid >> 2, scol = (tid & 3) << 4;
    const int kOff = z * Ksub;
    const unsigned char* gA = A + (size_t)(m0 + srow) * Kfull + kOff + scol;
    const unsigned char* gB = W8 + (size_t)(n0 + srow) * Kfull + kOff + scol;
    constexpr int PA = (MR * 32 + 63) / 64;
    constexpr int PB = (NR * 32 + 63) / 64;

    f32x4 acc[MR][NR];
#pragma unroll
    for (int i = 0; i < MR; ++i)
#pragma unroll
        for (int j = 0; j < NR; ++j) acc[i][j] = (f32x4){0.f, 0.f, 0.f, 0.f};

    uint4 ra[PA], rb[PB];
#pragma unroll
    for (int p = 0; p < PA; ++p)
        if (p * 64 + srow < MR * 32) ra[p] = *(const uint4*)(gA + (size_t)p * 64 * Kfull);
#pragma unroll
    for (int p = 0; p < PB; ++p)
        if (p * 64 + srow < NR * 32) rb[p] = *(const uint4*)(gB + (size_t)p * 64 * Kfull);

    for (int kt = 0; kt < Ksub; kt += 64) {
#pragma unroll
        for (int p = 0; p < PA; ++p)
            if (p * 64 + srow < MR * 32)
                *(uint4*)&lA[(p * 64 + srow) * LSTR8 + scol] = ra[p];
#pragma unroll
        for (int p = 0; p < PB; ++p)
            if (p * 64 + srow < NR * 32)
                *(uint4*)&lB[(p * 64 + srow) * LSTR8 + scol] = rb[p];
        __syncthreads();
        if (kt + 64 < Ksub) {   // prefetch next K-tile into regs (overlaps MFMA)
#pragma unroll
            for (int p = 0; p < PA; ++p)
                if (p * 64 + srow < MR * 32) ra[p] = *(const uint4*)(gA + (size_t)p * 64 * Kfull + kt + 64);
#pragma unroll
            for (int p = 0; p < PB; ++p)
                if (p * 64 + srow < NR * 32) rb[p] = *(const uint4*)(gB + (size_t)p * 64 * Kfull + kt + 64);
        }
#pragma unroll
        for (int ks = 0; ks < 2; ++ks) {
            long long af[MR], bfr[NR];
#pragma unroll
            for (int m = 0; m < MR; ++m)
                af[m] = *(const long long*)&lA[(wr * (MR * 16) + (m << 4) + lr) * LSTR8 + ks * 32 + (kg << 3)];
#pragma unroll
            for (int n = 0; n < NR; ++n)
                bfr[n] = *(const long long*)&lB[(wc * (NR * 16) + (n << 4) + lr) * LSTR8 + ks * 32 + (kg << 3)];
#pragma unroll
            for (int m = 0; m < MR; ++m)
#pragma unroll
                for (int n = 0; n < NR; ++n)
                    acc[m][n] = __builtin_amdgcn_mfma_f32_16x16x32_fp8_fp8(af[m], bfr[n], acc[m][n], 0, 0, 0);
        }
        __syncthreads();
    }

    const int rbase = m0 + wr * (MR * 16) + (kg << 2);
    const int cbase = n0 + wc * (NR * 16) + lr;
#pragma unroll
    for (int m = 0; m < MR; ++m) {
#pragma unroll
        for (int n = 0; n < NR; ++n) {
            const int col = cbase + (n << 4);
            const float bv = (z == 0) ? bias[col] : 0.f;
#pragma unroll
            for (int j = 0; j < 4; ++j) {
                const int row = rbase + (m << 4) + j;
                float v = acc[m][n][j] * WINV + bv;
                if (ACT == 1) v = 0.5f * v * (1.0f + erff(v * 0.70710678118654752440f));
                if (OUT8) {
                    C8[(size_t)z * splitStride + (size_t)row * N + col] = f2e4m3(v);
                } else {
                    Cb[(size_t)z * splitStride + (size_t)row * N + col] = f2bf(v);
                }
            }
        }
    }
}

// ---------------- MFMA attention (bf16): block = (b, h, 128-q-half); fp8 ctx out ----------------
__global__ __launch_bounds__(256, 2)
void attn_mfma(const unsigned short* __restrict__ qkv,
               unsigned char* __restrict__ ctx8) {
    __shared__ unsigned short Ks[256 * 72];
    __shared__ unsigned short Vt[64 * 264];
    __shared__ unsigned short Ps[4][16 * 72];

    int f = blockIdx.x;
    f = (f & 7) * 48 + (f >> 3);
    const int half = f & 1;
    const int hh = (f >> 1) % NH;
    const int b = f / (2 * NH);
    const int t = threadIdx.x;
    const int l = t & 63, w = t >> 6;
    const int l15 = l & 15, g = l >> 4;

    {
        const int c0 = (t & 7) << 3;
        int r = t >> 3;
#pragma unroll
        for (int it = 0; it < 8; ++it, r += 32) {
            u16x8 kv = *(const u16x8*)&qkv[(size_t)(b * S + r) * QKVS + H + hh * 64 + c0];
            *(u16x8*)&Ks[r * 72 + c0] = kv;
        }
    }
    {
        const int d0 = (t & 7) << 3;
        int s = t >> 3;
#pragma unroll
        for (int it = 0; it < 8; ++it, s += 32) {
            u16x8 vv = *(const u16x8*)&qkv[(size_t)(b * S + s) * QKVS + 2 * H + hh * 64 + d0];
#pragma unroll
            for (int j = 0; j < 8; ++j) {
                int d = d0 + j;
                Vt[d * 264 + (s ^ (((d >> 3) & 7) << 3))] = vv[j];
            }
        }
    }
    __syncthreads();

    unsigned short* ps = Ps[w];
#pragma unroll
    for (int qi = 0; qi < 2; ++qi) {
        const int qrow = half * 128 + qi * 64 + w * 16 + l15;
        const unsigned short* qp = &qkv[(size_t)(b * S + qrow) * QKVS + hh * 64 + g * 8];
        bf16x8 aq0 = *(const bf16x8*)qp;
        bf16x8 aq1 = *(const bf16x8*)(qp + 32);

        f32x4 acc[16];
#pragma unroll
        for (int n = 0; n < 16; ++n) acc[n] = (f32x4){0.f, 0.f, 0.f, 0.f};
        __builtin_amdgcn_s_setprio(1);
#pragma unroll
        for (int n = 0; n < 16; ++n) {
            const unsigned short* kp = &Ks[(n * 16 + l15) * 72 + g * 8];
            bf16x8 b0 = *(const bf16x8*)kp;
            bf16x8 b1 = *(const bf16x8*)(kp + 32);
            acc[n] = __builtin_amdgcn_mfma_f32_16x16x32_bf16(aq0, b0, acc[n], 0, 0, 0);
            acc[n] = __builtin_amdgcn_mfma_f32_16x16x32_bf16(aq1, b1, acc[n], 0, 0, 0);
        }
        __builtin_amdgcn_s_setprio(0);

        float inv[4];
#pragma unroll
        for (int j = 0; j < 4; ++j) {
            float mx = acc[0][j];
#pragma unroll
            for (int n = 1; n < 16; ++n) mx = fmaxf(mx, acc[n][j]);
            mx = fmaxf(mx, __shfl_xor(mx, 1));
            mx = fmaxf(mx, __shfl_xor(mx, 2));
            mx = fmaxf(mx, __shfl_xor(mx, 4));
            mx = fmaxf(mx, __shfl_xor(mx, 8));
            float sum = 0.f;
#pragma unroll
            for (int n = 0; n < 16; ++n) {
                float e = exp2f((acc[n][j] - mx) * 0.18033688011112042f);
                acc[n][j] = e;
                sum += e;
            }
            sum += __shfl_xor(sum, 1);
            sum += __shfl_xor(sum, 2);
            sum += __shfl_xor(sum, 4);
            sum += __shfl_xor(sum, 8);
            inv[j] = 1.0f / sum;
        }

        f32x4 cacc[4];
#pragma unroll
        for (int nd = 0; nd < 4; ++nd) cacc[nd] = (f32x4){0.f, 0.f, 0.f, 0.f};
#pragma unroll
        for (int c = 0; c < 4; ++c) {
#pragma unroll
            for (int nl = 0; nl < 4; ++nl) {
                int n = c * 4 + nl;
#pragma unroll
                for (int j = 0; j < 4; ++j)
                    ps[(g * 4 + j) * 72 + nl * 16 + l15] = f2bf(acc[n][j]);
            }
            bf16x8 pa0 = *(const bf16x8*)&ps[l15 * 72 + g * 8];
            bf16x8 pa1 = *(const bf16x8*)&ps[l15 * 72 + 32 + g * 8];
            __builtin_amdgcn_s_setprio(1);
#pragma unroll
            for (int nd = 0; nd < 4; ++nd) {
                const int d = nd * 16 + l15;
                const int swz = ((d >> 3) & 7) << 3;
                const unsigned short* vp0 = &Vt[d * 264 + ((c * 64 + g * 8) ^ swz)];
                const unsigned short* vp1 = &Vt[d * 264 + ((c * 64 + 32 + g * 8) ^ swz)];
                bf16x8 v0 = *(const bf16x8*)vp0;
                bf16x8 v1 = *(const bf16x8*)vp1;
                cacc[nd] = __builtin_amdgcn_mfma_f32_16x16x32_bf16(pa0, v0, cacc[nd], 0, 0, 0);
                cacc[nd] = __builtin_amdgcn_mfma_f32_16x16x32_bf16(pa1, v1, cacc[nd], 0, 0, 0);
            }
            __builtin_amdgcn_s_setprio(0);
        }

#pragma unroll
        for (int nd = 0; nd < 4; ++nd)
#pragma unroll
            for (int j = 0; j < 4; ++j) {
                int qr = half * 128 + qi * 64 + w * 16 + g * 4 + j;
                ctx8[(size_t)(b * S + qr) * H + hh * 64 + nd * 16 + l15] = f2e4m3(cacc[nd][j] * inv[j]);
            }
    }
}

// ---------------- Classifier: one wave per row (bf16 h) ----------------
__global__ void clf_kernel(const unsigned short* __restrict__ hb,
                           const float* __restrict__ W,
                           const float* __restrict__ bias,
                           float* __restrict__ logits) {
    const int row = blockIdx.x * 4 + (threadIdx.x >> 6);
    const int l = threadIdx.x & 63;
    const unsigned short* hp = hb + (size_t)row * H;
    float acc[T] = {};
#pragma unroll
    for (int i = 0; i < 12; ++i) {
        const int k = l + (i << 6);
        const float x = bf2f(hp[k]);
        const float* wp = &W[k * T];
#pragma unroll
        for (int n = 0; n < T; ++n) acc[n] += x * wp[n];
    }
#pragma unroll
    for (int o = 32; o; o >>= 1)
#pragma unroll
        for (int n = 0; n < T; ++n) acc[n] += __shfl_xor(acc[n], o);
    if (l < T) logits[(size_t)row * T + l] = acc[l] + bias[l];
}

// ---------------- CRF chunk: 9x9 transfer-matrix product over 16 steps (log-semiring) ----------------
__global__ void crf_chunk_kernel(const float* __restrict__ logits,
                                 const int* __restrict__ target,
                                 const float* __restrict__ trans,
                                 float* __restrict__ Tc) {
    const int blk = blockIdx.x;
    const int b = blk >> 4, c = blk & 15;
    const int t = threadIdx.x;     // 128
    const int i = t / 9, j = t - i * 9;
    const bool act = t < 81;
    __shared__ float Tb[2][81];
    const float* lg = logits + (size_t)b * S * T;
    const int* tg = target + b * S;
    const float K2 = 1.44269504088896340736f;
    const float IK = 0.69314718055994530942f;

    float trc[T];
    if (act) {
#pragma unroll
        for (int k = 0; k < T; ++k) trc[k] = trans[k * T + j];
        Tb[0][t] = (i == j) ? 0.f : -1e30f;
    }
    __syncthreads();

    int p = 0;
    const int s0 = c * 16 + 1;
    const int s1 = (c == 15) ? S : (s0 + 16);
    for (int s = s0; s < s1; ++s) {
        if (tg[s] > -1) {
            if (act) {
                const float em = lg[s * T + j];
                float v[T];
#pragma unroll
                for (int k = 0; k < T; ++k) v[k] = Tb[p][i * 9 + k] + trc[k];
                float mx = fmaxf(v[0], v[1]);
                mx = fmaxf(mx, fmaxf(v[2], v[3]));
                mx = fmaxf(mx, fmaxf(v[4], v[5]));
                mx = fmaxf(mx, fmaxf(v[6], v[7]));
                mx = fmaxf(mx, v[8]);
                float sum = 0.f;
#pragma unroll
                for (int k = 0; k < T; ++k) sum += exp2f((v[k] - mx) * K2);
                Tb[p ^ 1][t] = mx + IK * log2f(sum) + em;
            }
            __syncthreads();
            p ^= 1;
        }
    }
    if (act) Tc[(size_t)blk * 81 + t] = Tb[p][t];
}

// ---------------- CRF final: numerator + chunk combine + denominator + mean, one block ----------------
__global__ __launch_bounds__(1024)
void crf_final_kernel(const float* __restrict__ logits,
                      const int* __restrict__ target,
                      const float* __restrict__ start,
                      const float* __restrict__ trans,
                      const float* __restrict__ endv,
                      const float* __restrict__ Tc,
                      float* __restrict__ out) {
    const int t = threadIdx.x;   // 1024 = 16 waves; wave = batch
    const int b = t >> 6, l = t & 63;
    const float* lg = logits + (size_t)b * S * T;
    const int* tg = target + b * S;
    const float K2 = 1.44269504088896340736f;
    const float IK = 0.69314718055994530942f;

    float pnum = 0.f; int pcnt = 0;
#pragma unroll
    for (int c = 0; c < 4; ++c) {
        const int s = 1 + l + (c << 6);
        if (s < S) {
            const int tcur = tg[s], tprev = tg[s - 1];
            const bool m = tcur > -1;
            const int tag = m ? tcur : 0;
            const int ptag = (tprev > -1) ? tprev : 0;
            if (m) { pnum += trans[ptag * T + tag] + lg[s * T + tag]; pcnt += 1; }
        }
    }
#pragma unroll
    for (int o = 32; o; o >>= 1) { pnum += __shfl_xor(pnum, o); pcnt += __shfl_xor(pcnt, o); }

    const int jj = (l < T) ? l : 0;
    float a = start[jj] + lg[jj];
    for (int c = 0; c < NCH; ++c) {
        const float* Tm = Tc + ((size_t)(b * NCH + c)) * 81;
        float v[T];
#pragma unroll
        for (int i2 = 0; i2 < T; ++i2) v[i2] = __shfl(a, i2) + Tm[i2 * 9 + jj];
        float mx = fmaxf(v[0], v[1]);
        mx = fmaxf(mx, fmaxf(v[2], v[3]));
        mx = fmaxf(mx, fmaxf(v[4], v[5]));
        mx = fmaxf(mx, fmaxf(v[6], v[7]));
        mx = fmaxf(mx, v[8]);
        float sum = 0.f;
#pragma unroll
        for (int k = 0; k < T; ++k) sum += exp2f((v[k] - mx) * K2);
        a = mx + IK * log2f(sum);
    }

    float val = (l < T) ? (a + endv[jj]) : -1e30f;
    float mx = val;
#pragma unroll
    for (int o = 8; o; o >>= 1) mx = fmaxf(mx, __shfl_xor(mx, o));
    float sm = (l < T) ? exp2f((val - mx) * K2) : 0.f;
#pragma unroll
    for (int o = 8; o; o >>= 1) sm += __shfl_xor(sm, o);
    const float denom = mx + IK * log2f(sm);

    __shared__ float part[16];
    if (l == 0) {
        const bool m0 = tg[0] > -1;
        const int tag0 = m0 ? tg[0] : 0;
        const int cnt = pcnt + (m0 ? 1 : 0);
        int lastIdx = cnt - 1; if (lastIdx < 0) lastIdx = 0;
        const int lt = tg[lastIdx];
        const int lastTag = (lt > -1) ? lt : 0;
        const float num = start[tag0] + lg[tag0] + pnum + endv[lastTag];
        part[b] = num - denom;
    }
    __syncthreads();
    if (t == 0) {
        float s = 0.f;
#pragma unroll
        for (int i = 0; i < 16; ++i) s += part[i];
        out[0] = -s * (1.0f / 16.0f);
    }
}

// ---------------- Host launch ----------------
extern "C" void kernel_launch(void* const* d_in, const int* in_sizes, int n_in,
                              void* d_out, int out_size, void* d_ws, size_t ws_size,
                              hipStream_t stream) {
    const int*   x        = (const int*)d_in[0];
    const int*   target   = (const int*)d_in[1];
    const float* word_emb = (const float*)d_in[2];
    const float* pos_emb  = (const float*)d_in[3];
    const float* type_emb = (const float*)d_in[4];
    const float* emb_ln_g = (const float*)d_in[5];
    const float* emb_ln_b = (const float*)d_in[6];
    const float* Wq = (const float*)d_in[7];
    const float* bq = (const float*)d_in[8];
    const float* Wk = (const float*)d_in[9];
    const float* bk = (const float*)d_in[10];
    const float* Wv = (const float*)d_in[11];
    const float* bv = (const float*)d_in[12];
    const float* Wo = (const float*)d_in[13];
    const float* bo = (const float*)d_in[14];
    const float* ln1_g = (const float*)d_in[15];
    const float* ln1_b = (const float*)d_in[16];
    const float* W1 = (const float*)d_in[17];
    const float* b1 = (const float*)d_in[18];
    const float* W2 = (const float*)d_in[19];
    const float* b2 = (const float*)d_in[20];
    const float* ln2_g = (const float*)d_in[21];
    const float* ln2_b = (const float*)d_in[22];
    const float* clf_W = (const float*)d_in[23];
    const float* clf_b = (const float*)d_in[24];
    const float* crf_start = (const float*)d_in[25];
    const float* crf_trans = (const float*)d_in[26];
    const float* crf_end   = (const float*)d_in[27];

    char* ws = (char*)d_ws;
    size_t off = 0;
    auto alloc = [&](size_t bytes) { void* p = ws + off; off += (bytes + 255) & ~255ull; return p; };

    unsigned char*  wqkv8 = (unsigned char*)alloc((size_t)L * 3 * H * H);
    unsigned char*  wo8   = (unsigned char*)alloc((size_t)L * H * H);
    unsigned char*  w18   = (unsigned char*)alloc((size_t)L * H * DFF);
    unsigned char*  w28   = (unsigned char*)alloc((size_t)L * H * DFF);
    float*          bcat  = (float*)alloc((size_t)L * QKVS * 4);
    unsigned short* hb    = (unsigned short*)alloc(MH * 2);
    unsigned char*  hb8   = (unsigned char*)alloc(MH);
    unsigned short* qkvb  = (unsigned short*)alloc((size_t)M * QKVS * 2);
    unsigned char*  ctx8  = (unsigned char*)alloc(MH);
    unsigned short* gob   = (unsigned short*)alloc(4 * MH * 2);   // up to 4 K-split partials
    unsigned char*  ff8   = (unsigned char*)alloc((size_t)M * DFF);
    float*          logits = (float*)alloc((size_t)M * T * 4);
    float*          Tcbuf  = (float*)alloc((size_t)B * NCH * 81 * 4);

    dim3 tb(32, 8);
    convT4_kernel<<<dim3(H / 32, H / 32, 4 * L), tb, 0, stream>>>(Wq, Wk, Wv, Wo, wqkv8, wo8);
    convT_kernel<<<dim3(DFF / 32, H / 32, L), tb, 0, stream>>>(W1, w18, H, DFF, (size_t)H * DFF);
    convT_kernel<<<dim3(H / 32, DFF / 32, L), tb, 0, stream>>>(W2, w28, DFF, H, (size_t)H * DFF);
    biascat_kernel<<<(L * QKVS + 255) / 256, 256, 0, stream>>>(bq, bk, bv, bcat);

    embed_ln_kernel<<<M, 192, 0, stream>>>(x, word_emb, pos_emb, type_emb, emb_ln_g, emb_ln_b, hb, hb8);

    const dim3 gQKV(QKVS / 96, M / 128, 1);   // 24 x 32      (MR=4, NR=3 -> 768 blocks)
    const dim3 gFF1(DFF / 128, M / 128, 1);   // 24 x 32      (MR=4, NR=4 -> 768 blocks)
    const dim3 gWo (H / 128, M / 64, 2);      // 6 x 64 x 2   (MR=2, NR=4, K-split 2 -> 768)
    const dim3 gFF2(H / 128, M / 64, 4);      // 6 x 64 x 4   (MR=2, NR=4, K-split 4 -> 1536)

    for (int l = 0; l < L; ++l) {
        gemm_fp8<0, 4, 3, 0><<<gQKV, 256, 0, stream>>>(hb8, wqkv8 + (size_t)l * 3 * H * H, bcat + l * QKVS,
                                                       qkvb, nullptr, H, H, QKVS, 0);
        attn_mfma<<<B * NH * 2, 256, 0, stream>>>(qkvb, ctx8);
        gemm_fp8<0, 2, 4, 0><<<gWo, 256, 0, stream>>>(ctx8, wo8 + (size_t)l * H * H, bo + l * H,
                                                      gob, nullptr, H / 2, H, H, MH);
        residual_ln_kernel<2><<<M, 192, 0, stream>>>(hb, hb8, gob, ln1_g + l * H, ln1_b + l * H);
        gemm_fp8<1, 4, 4, 1><<<gFF1, 256, 0, stream>>>(hb8, w18 + (size_t)l * H * DFF, b1 + l * DFF,
                                                       nullptr, ff8, H, H, DFF, 0);
        gemm_fp8<0, 2, 4, 0><<<gFF2, 256, 0, stream>>>(ff8, w28 + (size_t)l * H * DFF, b2 + l * H,
                                                       gob, nullptr, DFF / 4, DFF, H, MH);
        residual_ln_kernel<4><<<M, 192, 0, stream>>>(hb, hb8, gob, ln2_g + l * H, ln2_b + l * H);
    }

    clf_kernel<<<M / 4, 256, 0, stream>>>(hb, clf_W, clf_b, logits);
    crf_chunk_kernel<<<B * NCH, 128, 0, stream>>>(logits, target, crf_trans, Tcbuf);
    crf_final_kernel<<<1, 1024, 0, stream>>>(logits, target, crf_start, crf_trans, crf_end, Tcbuf, (float*)d_out);
}

// Round 16
// 1701.372 us; speedup vs baseline: 1.5888x; 1.5888x over previous
//
#include <hip/hip_runtime.h>
#include <math.h>

#define B 16
#define S 256
#define H 768
#define NH 12
#define DH 64
#define DFF 3072
#define L 12
#define T 9
#define M (B*S)
#define LN_EPS 1e-12f
#define QKVS (3*H)
#define NCH 16   // CRF chunks per batch
#define MH ((size_t)M * H)

typedef __attribute__((ext_vector_type(8))) __bf16 bf16x8;
typedef __attribute__((ext_vector_type(8))) unsigned short u16x8;
typedef __attribute__((ext_vector_type(4))) unsigned short u16x4;
typedef __attribute__((ext_vector_type(4))) float f32x4;

__device__ __forceinline__ unsigned short f2bf(float f) {
    unsigned int u = __float_as_uint(f);
    unsigned int r = u + 0x7fffu + ((u >> 16) & 1u);
    return (unsigned short)(r >> 16);
}
__device__ __forceinline__ float bf2f(unsigned short h) {
    return __uint_as_float((unsigned int)h << 16);
}

// ---------------- Merged weight convert+transpose for the 4 HxH weights ----------------
__global__ void convT4_kernel(const float* __restrict__ Wq, const float* __restrict__ Wk,
                              const float* __restrict__ Wv, const float* __restrict__ Wo,
                              unsigned short* __restrict__ wqkvT, unsigned short* __restrict__ woT) {
    __shared__ float tile[32][33];
    const int z = blockIdx.z;
    const int which = z / L, layer = z - which * L;
    const float* Wp = (which == 0 ? Wq : which == 1 ? Wk : which == 2 ? Wv : Wo)
                      + (size_t)layer * H * H;
    unsigned short* Tp = (which < 3)
        ? wqkvT + (size_t)layer * 3 * H * H + (size_t)which * H * H
        : woT + (size_t)layer * H * H;
    const int n0 = blockIdx.x * 32, k0 = blockIdx.y * 32;
    const int tx = threadIdx.x, ty = threadIdx.y;  // 32 x 8
#pragma unroll
    for (int i = 0; i < 32; i += 8)
        tile[ty + i][tx] = Wp[(size_t)(k0 + ty + i) * H + n0 + tx];
    __syncthreads();
    {
        const int u = ty * 32 + tx;
        const int r = u >> 3, kq = (u & 7) << 2;
        u16x4 o;
#pragma unroll
        for (int j = 0; j < 4; ++j) o[j] = f2bf(tile[kq + j][r]);
        *(u16x4*)&Tp[(size_t)(n0 + r) * H + k0 + kq] = o;
    }
}

// ---------------- Weight convert + transpose (generic): W (K x N) f32 -> WT (N x K) bf16 ----------------
__global__ void convT_kernel(const float* __restrict__ W, unsigned short* __restrict__ WT,
                             int K, int N, size_t dstLayerStride) {
    __shared__ float tile[32][33];
    const int layer = blockIdx.z;
    const float* Wp = W + (size_t)layer * K * N;
    unsigned short* Tp = WT + (size_t)layer * dstLayerStride;
    const int n0 = blockIdx.x * 32, k0 = blockIdx.y * 32;
    const int tx = threadIdx.x, ty = threadIdx.y;  // 32 x 8
#pragma unroll
    for (int i = 0; i < 32; i += 8)
        tile[ty + i][tx] = Wp[(size_t)(k0 + ty + i) * N + n0 + tx];
    __syncthreads();
    {
        const int u = ty * 32 + tx;
        const int r = u >> 3, kq = (u & 7) << 2;
        u16x4 o;
#pragma unroll
        for (int j = 0; j < 4; ++j) o[j] = f2bf(tile[kq + j][r]);
        *(u16x4*)&Tp[(size_t)(n0 + r) * K + k0 + kq] = o;
    }
}

// ---------------- Concat QKV biases per layer: [L][2304] ----------------
__global__ void biascat_kernel(const float* __restrict__ bq, const float* __restrict__ bk,
                               const float* __restrict__ bv, float* __restrict__ out) {
    int idx = blockIdx.x * 256 + threadIdx.x;
    if (idx >= L * QKVS) return;
    int l = idx / QKVS, c = idx % QKVS;
    float v = (c < H) ? bq[l * H + c] : (c < 2 * H) ? bk[l * H + c - H] : bv[l * H + c - 2 * H];
    out[idx] = v;
}

// ---------------- Embedding + LayerNorm (192 threads, float4 in, bf16 out) ----------------
__global__ void embed_ln_kernel(const int* __restrict__ x,
                                const float* __restrict__ word_emb,
                                const float* __restrict__ pos_emb,
                                const float* __restrict__ type_emb,
                                const float* __restrict__ g,
                                const float* __restrict__ bta,
                                unsigned short* __restrict__ hb) {
    const int row = blockIdx.x;
    const int s = row % S;
    const int tok = x[row];
    const int t = threadIdx.x;     // 192
    const int c = t << 2;
    const float4 wv = *(const float4*)&word_emb[(size_t)tok * H + c];
    const float4 pv = *(const float4*)&pos_emb[s * H + c];
    const float4 tv = *(const float4*)&type_emb[c];
    float v[4] = {wv.x + pv.x + tv.x, wv.y + pv.y + tv.y, wv.z + pv.z + tv.z, wv.w + pv.w + tv.w};
    float s1 = v[0] + v[1] + v[2] + v[3];
    float s2 = v[0]*v[0] + v[1]*v[1] + v[2]*v[2] + v[3]*v[3];
#pragma unroll
    for (int o = 32; o; o >>= 1) { s1 += __shfl_xor(s1, o); s2 += __shfl_xor(s2, o); }
    __shared__ float ws[3][2];
    const int w = t >> 6, l = t & 63;
    if (l == 0) { ws[w][0] = s1; ws[w][1] = s2; }
    __syncthreads();
    const float S1 = ws[0][0] + ws[1][0] + ws[2][0];
    const float S2 = ws[0][1] + ws[1][1] + ws[2][1];
    const float mean = S1 * (1.0f / H);
    const float var = fmaxf(S2 * (1.0f / H) - mean * mean, 0.f);
    const float inv = rsqrtf(var + LN_EPS);
    const float4 gv = *(const float4*)&g[c];
    const float4 bv = *(const float4*)&bta[c];
    u16x4 ob;
    ob[0] = f2bf((v[0] - mean) * inv * gv.x + bv.x);
    ob[1] = f2bf((v[1] - mean) * inv * gv.y + bv.y);
    ob[2] = f2bf((v[2] - mean) * inv * gv.z + bv.z);
    ob[3] = f2bf((v[3] - mean) * inv * gv.w + bv.w);
    *(u16x4*)&hb[(size_t)row * H + c] = ob;
}

// ---------------- Residual + LayerNorm (bf16 stream; sums NS stacked delta partials) ----------------
template<int NS>
__global__ void residual_ln_kernel(unsigned short* __restrict__ hb,
                                   const unsigned short* __restrict__ delta,
                                   const float* __restrict__ g,
                                   const float* __restrict__ bta) {
    const int row = blockIdx.x;
    const int t = threadIdx.x;     // 192
    const int c = t << 2;
    const size_t base = (size_t)row * H + c;
    const u16x4 hv4 = *(const u16x4*)&hb[base];
    float v[4] = {bf2f(hv4[0]), bf2f(hv4[1]), bf2f(hv4[2]), bf2f(hv4[3])};
#pragma unroll
    for (int sgm = 0; sgm < NS; ++sgm) {
        const u16x4 dv4 = *(const u16x4*)&delta[sgm * MH + base];
#pragma unroll
        for (int j = 0; j < 4; ++j) v[j] += bf2f(dv4[j]);
    }
    float s1 = v[0] + v[1] + v[2] + v[3];
    float s2 = v[0]*v[0] + v[1]*v[1] + v[2]*v[2] + v[3]*v[3];
#pragma unroll
    for (int o = 32; o; o >>= 1) { s1 += __shfl_xor(s1, o); s2 += __shfl_xor(s2, o); }
    __shared__ float ws[3][2];
    const int w = t >> 6, l = t & 63;
    if (l == 0) { ws[w][0] = s1; ws[w][1] = s2; }
    __syncthreads();
    const float S1 = ws[0][0] + ws[1][0] + ws[2][0];
    const float S2 = ws[0][1] + ws[1][1] + ws[2][1];
    const float mean = S1 * (1.0f / H);
    const float var = fmaxf(S2 * (1.0f / H) - mean * mean, 0.f);
    const float inv = rsqrtf(var + LN_EPS);
    const float4 gv = *(const float4*)&g[c];
    const float4 bv = *(const float4*)&bta[c];
    u16x4 ob;
    ob[0] = f2bf((v[0] - mean) * inv * gv.x + bv.x);
    ob[1] = f2bf((v[1] - mean) * inv * gv.y + bv.y);
    ob[2] = f2bf((v[2] - mean) * inv * gv.z + bv.z);
    ob[3] = f2bf((v[3] - mean) * inv * gv.w + bv.w);
    *(u16x4*)&hb[base] = ob;
}

#define LSTR 72

// ---------------- bf16 MFMA GEMM: C = A @ WT^T (+ bias on split 0) ----------------
// Tile (MR*32) x (NR*32), 4 waves (2x2). Reg-staged padded LDS, BK=64, 3 blocks/CU.
// K-split via blockIdx.z. XCD-aware swizzle over the (x,y) plane.
template<int ACT, int MR, int NR>
__global__ __launch_bounds__(256, 3)
void gemm_bf16(const unsigned short* __restrict__ A,
               const unsigned short* __restrict__ WT,
               const float* __restrict__ bias,
               unsigned short* __restrict__ Cb,
               int Ksub, int Kfull, int N, size_t splitStride) {
    __shared__ unsigned short lA[MR * 32 * LSTR];
    __shared__ unsigned short lB[NR * 32 * LSTR];
    const int tid = threadIdx.x;
    const int z = blockIdx.z;
    // XCD swizzle (nb % 8 == 0 for all our grids)
    const int gx = gridDim.x;
    const int nb = gx * gridDim.y;
    int f = blockIdx.y * gx + blockIdx.x;
    f = (f & 7) * (nb >> 3) + (f >> 3);
    const int m0 = (f / gx) * (MR * 32), n0 = (f % gx) * (NR * 32);
    const int l = tid & 63, w = tid >> 6;
    const int wr = w >> 1, wc = w & 1;
    const int lr = l & 15, kg = l >> 4;

    const int srow = tid >> 3, scol = (tid & 7) << 3;
    const int kOff = z * Ksub;
    const unsigned short* gA = A + (size_t)(m0 + srow) * Kfull + kOff + scol;
    const unsigned short* gB = WT + (size_t)(n0 + srow) * Kfull + kOff + scol;

    f32x4 acc[MR][NR];
#pragma unroll
    for (int i = 0; i < MR; ++i)
#pragma unroll
        for (int j = 0; j < NR; ++j) acc[i][j] = (f32x4){0.f, 0.f, 0.f, 0.f};

    u16x8 ra[MR], rb[NR];
#pragma unroll
    for (int p = 0; p < MR; ++p) ra[p] = *(const u16x8*)(gA + (size_t)p * 32 * Kfull);
#pragma unroll
    for (int p = 0; p < NR; ++p) rb[p] = *(const u16x8*)(gB + (size_t)p * 32 * Kfull);

    for (int kt = 0; kt < Ksub; kt += 64) {
#pragma unroll
        for (int p = 0; p < MR; ++p)
            *(u16x8*)&lA[(srow + p * 32) * LSTR + scol] = ra[p];
#pragma unroll
        for (int p = 0; p < NR; ++p)
            *(u16x8*)&lB[(srow + p * 32) * LSTR + scol] = rb[p];
        __syncthreads();
        if (kt + 64 < Ksub) {
#pragma unroll
            for (int p = 0; p < MR; ++p) ra[p] = *(const u16x8*)(gA + (size_t)p * 32 * Kfull + kt + 64);
#pragma unroll
            for (int p = 0; p < NR; ++p) rb[p] = *(const u16x8*)(gB + (size_t)p * 32 * Kfull + kt + 64);
        }
#pragma unroll
        for (int ks = 0; ks < 2; ++ks) {
            bf16x8 af[MR], bfr[NR];
#pragma unroll
            for (int m = 0; m < MR; ++m)
                af[m] = *(const bf16x8*)&lA[(wr * (MR * 16) + (m << 4) + lr) * LSTR + ks * 32 + (kg << 3)];
#pragma unroll
            for (int n = 0; n < NR; ++n)
                bfr[n] = *(const bf16x8*)&lB[((wc * (NR * 16)) + (n << 4) + lr) * LSTR + ks * 32 + (kg << 3)];
#pragma unroll
            for (int m = 0; m < MR; ++m)
#pragma unroll
                for (int n = 0; n < NR; ++n)
                    acc[m][n] = __builtin_amdgcn_mfma_f32_16x16x32_bf16(af[m], bfr[n], acc[m][n], 0, 0, 0);
        }
        __syncthreads();
    }

    unsigned short* Cz = Cb + (size_t)z * splitStride;
    const int rbase = m0 + wr * (MR * 16) + (kg << 2);
    const int cbase = n0 + wc * (NR * 16) + lr;
#pragma unroll
    for (int m = 0; m < MR; ++m) {
#pragma unroll
        for (int n = 0; n < NR; ++n) {
            const int col = cbase + (n << 4);
            const float bv = (z == 0) ? bias[col] : 0.f;
#pragma unroll
            for (int j = 0; j < 4; ++j) {
                const int row = rbase + (m << 4) + j;
                float v = acc[m][n][j] + bv;
                if (ACT == 1) v = 0.5f * v * (1.0f + erff(v * 0.70710678118654752440f));
                Cz[(size_t)row * N + col] = f2bf(v);
            }
        }
    }
}

// ---------------- MFMA attention: block = (b, h, 128-q-half); V transposed in-LDS ----------------
__global__ __launch_bounds__(256, 2)
void attn_mfma(const unsigned short* __restrict__ qkv,
               unsigned short* __restrict__ ctxb) {
    __shared__ unsigned short Ks[256 * 72];
    __shared__ unsigned short Vt[64 * 264];
    __shared__ unsigned short Ps[4][16 * 72];

    // XCD swizzle: 384 blocks -> 48 contiguous logical blocks per XCD
    int f = blockIdx.x;
    f = (f & 7) * 48 + (f >> 3);
    const int half = f & 1;
    const int hh = (f >> 1) % NH;
    const int b = f / (2 * NH);
    const int t = threadIdx.x;
    const int l = t & 63, w = t >> 6;
    const int l15 = l & 15, g = l >> 4;

    {
        const int c0 = (t & 7) << 3;
        int r = t >> 3;
#pragma unroll
        for (int it = 0; it < 8; ++it, r += 32) {
            u16x8 kv = *(const u16x8*)&qkv[(size_t)(b * S + r) * QKVS + H + hh * 64 + c0];
            *(u16x8*)&Ks[r * 72 + c0] = kv;
        }
    }
    {
        const int d0 = (t & 7) << 3;
        int s = t >> 3;
#pragma unroll
        for (int it = 0; it < 8; ++it, s += 32) {
            u16x8 vv = *(const u16x8*)&qkv[(size_t)(b * S + s) * QKVS + 2 * H + hh * 64 + d0];
#pragma unroll
            for (int j = 0; j < 8; ++j) {
                int d = d0 + j;
                Vt[d * 264 + (s ^ (((d >> 3) & 7) << 3))] = vv[j];
            }
        }
    }
    __syncthreads();

    unsigned short* ps = Ps[w];
#pragma unroll
    for (int qi = 0; qi < 2; ++qi) {
        const int qrow = half * 128 + qi * 64 + w * 16 + l15;
        const unsigned short* qp = &qkv[(size_t)(b * S + qrow) * QKVS + hh * 64 + g * 8];
        bf16x8 aq0 = *(const bf16x8*)qp;
        bf16x8 aq1 = *(const bf16x8*)(qp + 32);

        f32x4 acc[16];
#pragma unroll
        for (int n = 0; n < 16; ++n) acc[n] = (f32x4){0.f, 0.f, 0.f, 0.f};
        __builtin_amdgcn_s_setprio(1);
#pragma unroll
        for (int n = 0; n < 16; ++n) {
            const unsigned short* kp = &Ks[(n * 16 + l15) * 72 + g * 8];
            bf16x8 b0 = *(const bf16x8*)kp;
            bf16x8 b1 = *(const bf16x8*)(kp + 32);
            acc[n] = __builtin_amdgcn_mfma_f32_16x16x32_bf16(aq0, b0, acc[n], 0, 0, 0);
            acc[n] = __builtin_amdgcn_mfma_f32_16x16x32_bf16(aq1, b1, acc[n], 0, 0, 0);
        }
        __builtin_amdgcn_s_setprio(0);

        float inv[4];
#pragma unroll
        for (int j = 0; j < 4; ++j) {
            float mx = acc[0][j];
#pragma unroll
            for (int n = 1; n < 16; ++n) mx = fmaxf(mx, acc[n][j]);
            mx = fmaxf(mx, __shfl_xor(mx, 1));
            mx = fmaxf(mx, __shfl_xor(mx, 2));
            mx = fmaxf(mx, __shfl_xor(mx, 4));
            mx = fmaxf(mx, __shfl_xor(mx, 8));
            float sum = 0.f;
#pragma unroll
            for (int n = 0; n < 16; ++n) {
                float e = exp2f((acc[n][j] - mx) * 0.18033688011112042f);
                acc[n][j] = e;
                sum += e;
            }
            sum += __shfl_xor(sum, 1);
            sum += __shfl_xor(sum, 2);
            sum += __shfl_xor(sum, 4);
            sum += __shfl_xor(sum, 8);
            inv[j] = 1.0f / sum;
        }

        f32x4 cacc[4];
#pragma unroll
        for (int nd = 0; nd < 4; ++nd) cacc[nd] = (f32x4){0.f, 0.f, 0.f, 0.f};
#pragma unroll
        for (int c = 0; c < 4; ++c) {
#pragma unroll
            for (int nl = 0; nl < 4; ++nl) {
                int n = c * 4 + nl;
#pragma unroll
                for (int j = 0; j < 4; ++j)
                    ps[(g * 4 + j) * 72 + nl * 16 + l15] = f2bf(acc[n][j]);
            }
            bf16x8 pa0 = *(const bf16x8*)&ps[l15 * 72 + g * 8];
            bf16x8 pa1 = *(const bf16x8*)&ps[l15 * 72 + 32 + g * 8];
            __builtin_amdgcn_s_setprio(1);
#pragma unroll
            for (int nd = 0; nd < 4; ++nd) {
                const int d = nd * 16 + l15;
                const int swz = ((d >> 3) & 7) << 3;
                const unsigned short* vp0 = &Vt[d * 264 + ((c * 64 + g * 8) ^ swz)];
                const unsigned short* vp1 = &Vt[d * 264 + ((c * 64 + 32 + g * 8) ^ swz)];
                bf16x8 v0 = *(const bf16x8*)vp0;
                bf16x8 v1 = *(const bf16x8*)vp1;
                cacc[nd] = __builtin_amdgcn_mfma_f32_16x16x32_bf16(pa0, v0, cacc[nd], 0, 0, 0);
                cacc[nd] = __builtin_amdgcn_mfma_f32_16x16x32_bf16(pa1, v1, cacc[nd], 0, 0, 0);
            }
            __builtin_amdgcn_s_setprio(0);
        }

#pragma unroll
        for (int nd = 0; nd < 4; ++nd)
#pragma unroll
            for (int j = 0; j < 4; ++j) {
                int qr = half * 128 + qi * 64 + w * 16 + g * 4 + j;
                ctxb[(size_t)(b * S + qr) * H + hh * 64 + nd * 16 + l15] = f2bf(cacc[nd][j] * inv[j]);
            }
    }
}

// ---------------- Classifier: one wave per row (bf16 h) ----------------
__global__ void clf_kernel(const unsigned short* __restrict__ hb,
                           const float* __restrict__ W,
                           const float* __restrict__ bias,
                           float* __restrict__ logits) {
    const int row = blockIdx.x * 4 + (threadIdx.x >> 6);
    const int l = threadIdx.x & 63;
    const unsigned short* hp = hb + (size_t)row * H;
    float acc[T] = {};
#pragma unroll
    for (int i = 0; i < 12; ++i) {
        const int k = l + (i << 6);
        const float x = bf2f(hp[k]);
        const float* wp = &W[k * T];
#pragma unroll
        for (int n = 0; n < T; ++n) acc[n] += x * wp[n];
    }
#pragma unroll
    for (int o = 32; o; o >>= 1)
#pragma unroll
        for (int n = 0; n < T; ++n) acc[n] += __shfl_xor(acc[n], o);
    if (l < T) logits[(size_t)row * T + l] = acc[l] + bias[l];
}

// ---------------- CRF chunk: 9x9 transfer-matrix product over 16 steps (log-semiring) ----------------
__global__ void crf_chunk_kernel(const float* __restrict__ logits,
                                 const int* __restrict__ target,
                                 const float* __restrict__ trans,
                                 float* __restrict__ Tc) {
    const int blk = blockIdx.x;
    const int b = blk >> 4, c = blk & 15;
    const int t = threadIdx.x;     // 128
    const int i = t / 9, j = t - i * 9;
    const bool act = t < 81;
    __shared__ float Tb[2][81];
    const float* lg = logits + (size_t)b * S * T;
    const int* tg = target + b * S;
    const float K2 = 1.44269504088896340736f;
    const float IK = 0.69314718055994530942f;

    float trc[T];
    if (act) {
#pragma unroll
        for (int k = 0; k < T; ++k) trc[k] = trans[k * T + j];
        Tb[0][t] = (i == j) ? 0.f : -1e30f;
    }
    __syncthreads();

    int p = 0;
    const int s0 = c * 16 + 1;
    const int s1 = (c == 15) ? S : (s0 + 16);
    for (int s = s0; s < s1; ++s) {
        if (tg[s] > -1) {
            if (act) {
                const float em = lg[s * T + j];
                float v[T];
#pragma unroll
                for (int k = 0; k < T; ++k) v[k] = Tb[p][i * 9 + k] + trc[k];
                float mx = fmaxf(v[0], v[1]);
                mx = fmaxf(mx, fmaxf(v[2], v[3]));
                mx = fmaxf(mx, fmaxf(v[4], v[5]));
                mx = fmaxf(mx, fmaxf(v[6], v[7]));
                mx = fmaxf(mx, v[8]);
                float sum = 0.f;
#pragma unroll
                for (int k = 0; k < T; ++k) sum += exp2f((v[k] - mx) * K2);
                Tb[p ^ 1][t] = mx + IK * log2f(sum) + em;
            }
            __syncthreads();
            p ^= 1;
        }
    }
    if (act) Tc[(size_t)blk * 81 + t] = Tb[p][t];
}

// ---------------- CRF final: numerator + chunk combine + denominator + mean, one block ----------------
__global__ __launch_bounds__(1024)
void crf_final_kernel(const float* __restrict__ logits,
                      const int* __restrict__ target,
                      const float* __restrict__ start,
                      const float* __restrict__ trans,
                      const float* __restrict__ endv,
                      const float* __restrict__ Tc,
                      float* __restrict__ out) {
    const int t = threadIdx.x;   // 1024 = 16 waves; wave = batch
    const int b = t >> 6, l = t & 63;
    const float* lg = logits + (size_t)b * S * T;
    const int* tg = target + b * S;
    const float K2 = 1.44269504088896340736f;
    const float IK = 0.69314718055994530942f;

    float pnum = 0.f; int pcnt = 0;
#pragma unroll
    for (int c = 0; c < 4; ++c) {
        const int s = 1 + l + (c << 6);
        if (s < S) {
            const int tcur = tg[s], tprev = tg[s - 1];
            const bool m = tcur > -1;
            const int tag = m ? tcur : 0;
            const int ptag = (tprev > -1) ? tprev : 0;
            if (m) { pnum += trans[ptag * T + tag] + lg[s * T + tag]; pcnt += 1; }
        }
    }
#pragma unroll
    for (int o = 32; o; o >>= 1) { pnum += __shfl_xor(pnum, o); pcnt += __shfl_xor(pcnt, o); }

    const int jj = (l < T) ? l : 0;
    float a = start[jj] + lg[jj];
    for (int c = 0; c < NCH; ++c) {
        const float* Tm = Tc + ((size_t)(b * NCH + c)) * 81;
        float v[T];
#pragma unroll
        for (int i2 = 0; i2 < T; ++i2) v[i2] = __shfl(a, i2) + Tm[i2 * 9 + jj];
        float mx = fmaxf(v[0], v[1]);
        mx = fmaxf(mx, fmaxf(v[2], v[3]));
        mx = fmaxf(mx, fmaxf(v[4], v[5]));
        mx = fmaxf(mx, fmaxf(v[6], v[7]));
        mx = fmaxf(mx, v[8]);
        float sum = 0.f;
#pragma unroll
        for (int k = 0; k < T; ++k) sum += exp2f((v[k] - mx) * K2);
        a = mx + IK * log2f(sum);
    }

    float val = (l < T) ? (a + endv[jj]) : -1e30f;
    float mx = val;
#pragma unroll
    for (int o = 8; o; o >>= 1) mx = fmaxf(mx, __shfl_xor(mx, o));
    float sm = (l < T) ? exp2f((val - mx) * K2) : 0.f;
#pragma unroll
    for (int o = 8; o; o >>= 1) sm += __shfl_xor(sm, o);
    const float denom = mx + IK * log2f(sm);

    __shared__ float part[16];
    if (l == 0) {
        const bool m0 = tg[0] > -1;
        const int tag0 = m0 ? tg[0] : 0;
        const int cnt = pcnt + (m0 ? 1 : 0);
        int lastIdx = cnt - 1; if (lastIdx < 0) lastIdx = 0;
        const int lt = tg[lastIdx];
        const int lastTag = (lt > -1) ? lt : 0;
        const float num = start[tag0] + lg[tag0] + pnum + endv[lastTag];
        part[b] = num - denom;
    }
    __syncthreads();
    if (t == 0) {
        float s = 0.f;
#pragma unroll
        for (int i = 0; i < 16; ++i) s += part[i];
        out[0] = -s * (1.0f / 16.0f);
    }
}

// ---------------- Host launch ----------------
extern "C" void kernel_launch(void* const* d_in, const int* in_sizes, int n_in,
                              void* d_out, int out_size, void* d_ws, size_t ws_size,
                              hipStream_t stream) {
    const int*   x        = (const int*)d_in[0];
    const int*   target   = (const int*)d_in[1];
    const float* word_emb = (const float*)d_in[2];
    const float* pos_emb  = (const float*)d_in[3];
    const float* type_emb = (const float*)d_in[4];
    const float* emb_ln_g = (const float*)d_in[5];
    const float* emb_ln_b = (const float*)d_in[6];
    const float* Wq = (const float*)d_in[7];
    const float* bq = (const float*)d_in[8];
    const float* Wk = (const float*)d_in[9];
    const float* bk = (const float*)d_in[10];
    const float* Wv = (const float*)d_in[11];
    const float* bv = (const float*)d_in[12];
    const float* Wo = (const float*)d_in[13];
    const float* bo = (const float*)d_in[14];
    const float* ln1_g = (const float*)d_in[15];
    const float* ln1_b = (const float*)d_in[16];
    const float* W1 = (const float*)d_in[17];
    const float* b1 = (const float*)d_in[18];
    const float* W2 = (const float*)d_in[19];
    const float* b2 = (const float*)d_in[20];
    const float* ln2_g = (const float*)d_in[21];
    const float* ln2_b = (const float*)d_in[22];
    const float* clf_W = (const float*)d_in[23];
    const float* clf_b = (const float*)d_in[24];
    const float* crf_start = (const float*)d_in[25];
    const float* crf_trans = (const float*)d_in[26];
    const float* crf_end   = (const float*)d_in[27];

    char* ws = (char*)d_ws;
    size_t off = 0;
    auto alloc = [&](size_t bytes) { void* p = ws + off; off += (bytes + 255) & ~255ull; return p; };

    unsigned short* wqkvT = (unsigned short*)alloc((size_t)L * 3 * H * H * 2);
    unsigned short* woT   = (unsigned short*)alloc((size_t)L * H * H * 2);
    unsigned short* w1T   = (unsigned short*)alloc((size_t)L * H * DFF * 2);
    unsigned short* w2T   = (unsigned short*)alloc((size_t)L * H * DFF * 2);
    float*          bcat  = (float*)alloc((size_t)L * QKVS * 4);
    unsigned short* hb    = (unsigned short*)alloc(MH * 2);
    unsigned short* qkvb  = (unsigned short*)alloc((size_t)M * QKVS * 2);
    unsigned short* ctxb  = (unsigned short*)alloc(MH * 2);
    unsigned short* gob   = (unsigned short*)alloc(4 * MH * 2);   // K-split partials
    unsigned short* ffb   = (unsigned short*)alloc((size_t)M * DFF * 2);
    float*          logits = (float*)alloc((size_t)M * T * 4);
    float*          Tcbuf  = (float*)alloc((size_t)B * NCH * 81 * 4);

    dim3 tb(32, 8);
    convT4_kernel<<<dim3(H / 32, H / 32, 4 * L), tb, 0, stream>>>(Wq, Wk, Wv, Wo, wqkvT, woT);
    convT_kernel<<<dim3(DFF / 32, H / 32, L), tb, 0, stream>>>(W1, w1T, H, DFF, (size_t)H * DFF);
    convT_kernel<<<dim3(H / 32, DFF / 32, L), tb, 0, stream>>>(W2, w2T, DFF, H, (size_t)H * DFF);
    biascat_kernel<<<(L * QKVS + 255) / 256, 256, 0, stream>>>(bq, bk, bv, bcat);

    embed_ln_kernel<<<M, 192, 0, stream>>>(x, word_emb, pos_emb, type_emb, emb_ln_g, emb_ln_b, hb);

    const dim3 gQKV(QKVS / 96, M / 128, 1);   // 24 x 32      (MR=4, NR=3 -> 768 blocks = 3/CU)
    const dim3 gFF1(DFF / 128, M / 128, 1);   // 24 x 32      (MR=4, NR=4 -> 768 blocks)
    const dim3 gWo (H / 128, M / 64, 2);      // 6 x 64 x 2   (MR=2, NR=4, K-split 2 -> 768)
    const dim3 gFF2(H / 128, M / 64, 2);      // 6 x 64 x 2   (MR=2, NR=4, K-split 2 -> 768, Ksub=1536)

    for (int l = 0; l < L; ++l) {
        gemm_bf16<0, 4, 3><<<gQKV, 256, 0, stream>>>(hb, wqkvT + (size_t)l * 3 * H * H, bcat + l * QKVS,
                                                     qkvb, H, H, QKVS, 0);
        attn_mfma<<<B * NH * 2, 256, 0, stream>>>(qkvb, ctxb);
        gemm_bf16<0, 2, 4><<<gWo, 256, 0, stream>>>(ctxb, woT + (size_t)l * H * H, bo + l * H,
                                                    gob, H / 2, H, H, MH);
        residual_ln_kernel<2><<<M, 192, 0, stream>>>(hb, gob, ln1_g + l * H, ln1_b + l * H);
        gemm_bf16<1, 4, 4><<<gFF1, 256, 0, stream>>>(hb, w1T + (size_t)l * H * DFF, b1 + l * DFF,
                                                     ffb, H, H, DFF, 0);
        gemm_bf16<0, 2, 4><<<gFF2, 256, 0, stream>>>(ffb, w2T + (size_t)l * H * DFF, b2 + l * H,
                                                     gob, DFF / 2, DFF, H, MH);
        residual_ln_kernel<2><<<M, 192, 0, stream>>>(hb, gob, ln2_g + l * H, ln2_b + l * H);
    }

    clf_kernel<<<M / 4, 256, 0, stream>>>(hb, clf_W, clf_b, logits);
    crf_chunk_kernel<<<B * NCH, 128, 0, stream>>>(logits, target, crf_trans, Tcbuf);
    crf_final_kernel<<<1, 1024, 0, stream>>>(logits, target, crf_start, crf_trans, crf_end, Tcbuf, (float*)d_out);
}

// Round 17
// 1684.882 us; speedup vs baseline: 1.6043x; 1.0098x over previous
//
#include <hip/hip_runtime.h>
#include <math.h>

#define B 16
#define S 256
#define H 768
#define NH 12
#define DH 64
#define DFF 3072
#define L 12
#define T 9
#define M (B*S)
#define LN_EPS 1e-12f
#define QKVS (3*H)
#define NCH 16   // CRF chunks per batch
#define MH ((size_t)M * H)

typedef __attribute__((ext_vector_type(8))) __bf16 bf16x8;
typedef __attribute__((ext_vector_type(8))) unsigned short u16x8;
typedef __attribute__((ext_vector_type(4))) unsigned short u16x4;
typedef __attribute__((ext_vector_type(4))) float f32x4;

__device__ __forceinline__ unsigned short f2bf(float f) {
    unsigned int u = __float_as_uint(f);
    unsigned int r = u + 0x7fffu + ((u >> 16) & 1u);
    return (unsigned short)(r >> 16);
}
__device__ __forceinline__ float bf2f(unsigned short h) {
    return __uint_as_float((unsigned int)h << 16);
}
// fast GELU: v * u/(u+1), u = e^{2y}, y = 0.79788456(v + 0.044715 v^3); |err| <= ~3e-3
__device__ __forceinline__ float fast_gelu(float v) {
    float y = 0.7978845608028654f * (v + 0.044715f * v * v * v);
    y = fminf(y, 40.0f);
    float u = exp2f(y * 2.8853900817779268f);   // e^{2y}
    return v * (u / (u + 1.0f));
}

// ---------------- Merged weight convert+transpose for the 4 HxH weights ----------------
__global__ void convT4_kernel(const float* __restrict__ Wq, const float* __restrict__ Wk,
                              const float* __restrict__ Wv, const float* __restrict__ Wo,
                              unsigned short* __restrict__ wqkvT, unsigned short* __restrict__ woT) {
    __shared__ float tile[32][33];
    const int z = blockIdx.z;
    const int which = z / L, layer = z - which * L;
    const float* Wp = (which == 0 ? Wq : which == 1 ? Wk : which == 2 ? Wv : Wo)
                      + (size_t)layer * H * H;
    unsigned short* Tp = (which < 3)
        ? wqkvT + (size_t)layer * 3 * H * H + (size_t)which * H * H
        : woT + (size_t)layer * H * H;
    const int n0 = blockIdx.x * 32, k0 = blockIdx.y * 32;
    const int tx = threadIdx.x, ty = threadIdx.y;  // 32 x 8
#pragma unroll
    for (int i = 0; i < 32; i += 8)
        tile[ty + i][tx] = Wp[(size_t)(k0 + ty + i) * H + n0 + tx];
    __syncthreads();
    {
        const int u = ty * 32 + tx;
        const int r = u >> 3, kq = (u & 7) << 2;
        u16x4 o;
#pragma unroll
        for (int j = 0; j < 4; ++j) o[j] = f2bf(tile[kq + j][r]);
        *(u16x4*)&Tp[(size_t)(n0 + r) * H + k0 + kq] = o;
    }
}

// ---------------- Merged FF weight convert+transpose: W1 (HxDFF) and W2 (DFFxH) ----------------
// grid (DFF/32, H/32, 2L): which = z/L (0 -> W1, 1 -> W2, tile roles swapped).
__global__ void convTFF_kernel(const float* __restrict__ W1, const float* __restrict__ W2,
                               unsigned short* __restrict__ w1T, unsigned short* __restrict__ w2T) {
    __shared__ float tile[32][33];
    const int z = blockIdx.z;
    const int which = z / L, layer = z - which * L;
    const float* Wp; unsigned short* Tp; int Kd, Nd, n0, k0;
    if (which == 0) {            // W1: K=H, N=DFF
        Wp = W1 + (size_t)layer * H * DFF; Tp = w1T + (size_t)layer * H * DFF;
        Kd = H; Nd = DFF; n0 = blockIdx.x * 32; k0 = blockIdx.y * 32;
    } else {                     // W2: K=DFF, N=H (roles of bx/by swapped)
        Wp = W2 + (size_t)layer * H * DFF; Tp = w2T + (size_t)layer * H * DFF;
        Kd = DFF; Nd = H; n0 = blockIdx.y * 32; k0 = blockIdx.x * 32;
    }
    const int tx = threadIdx.x, ty = threadIdx.y;  // 32 x 8
#pragma unroll
    for (int i = 0; i < 32; i += 8)
        tile[ty + i][tx] = Wp[(size_t)(k0 + ty + i) * Nd + n0 + tx];
    __syncthreads();
    {
        const int u = ty * 32 + tx;
        const int r = u >> 3, kq = (u & 7) << 2;
        u16x4 o;
#pragma unroll
        for (int j = 0; j < 4; ++j) o[j] = f2bf(tile[kq + j][r]);
        *(u16x4*)&Tp[(size_t)(n0 + r) * Kd + k0 + kq] = o;
    }
}

// ---------------- Concat QKV biases per layer: [L][2304] ----------------
__global__ void biascat_kernel(const float* __restrict__ bq, const float* __restrict__ bk,
                               const float* __restrict__ bv, float* __restrict__ out) {
    int idx = blockIdx.x * 256 + threadIdx.x;
    if (idx >= L * QKVS) return;
    int l = idx / QKVS, c = idx % QKVS;
    float v = (c < H) ? bq[l * H + c] : (c < 2 * H) ? bk[l * H + c - H] : bv[l * H + c - 2 * H];
    out[idx] = v;
}

// ---------------- Embedding + LayerNorm (192 threads, float4 in, bf16 out) ----------------
__global__ void embed_ln_kernel(const int* __restrict__ x,
                                const float* __restrict__ word_emb,
                                const float* __restrict__ pos_emb,
                                const float* __restrict__ type_emb,
                                const float* __restrict__ g,
                                const float* __restrict__ bta,
                                unsigned short* __restrict__ hb) {
    const int row = blockIdx.x;
    const int s = row % S;
    const int tok = x[row];
    const int t = threadIdx.x;     // 192
    const int c = t << 2;
    const float4 wv = *(const float4*)&word_emb[(size_t)tok * H + c];
    const float4 pv = *(const float4*)&pos_emb[s * H + c];
    const float4 tv = *(const float4*)&type_emb[c];
    float v[4] = {wv.x + pv.x + tv.x, wv.y + pv.y + tv.y, wv.z + pv.z + tv.z, wv.w + pv.w + tv.w};
    float s1 = v[0] + v[1] + v[2] + v[3];
    float s2 = v[0]*v[0] + v[1]*v[1] + v[2]*v[2] + v[3]*v[3];
#pragma unroll
    for (int o = 32; o; o >>= 1) { s1 += __shfl_xor(s1, o); s2 += __shfl_xor(s2, o); }
    __shared__ float ws[3][2];
    const int w = t >> 6, l = t & 63;
    if (l == 0) { ws[w][0] = s1; ws[w][1] = s2; }
    __syncthreads();
    const float S1 = ws[0][0] + ws[1][0] + ws[2][0];
    const float S2 = ws[0][1] + ws[1][1] + ws[2][1];
    const float mean = S1 * (1.0f / H);
    const float var = fmaxf(S2 * (1.0f / H) - mean * mean, 0.f);
    const float inv = rsqrtf(var + LN_EPS);
    const float4 gv = *(const float4*)&g[c];
    const float4 bv = *(const float4*)&bta[c];
    u16x4 ob;
    ob[0] = f2bf((v[0] - mean) * inv * gv.x + bv.x);
    ob[1] = f2bf((v[1] - mean) * inv * gv.y + bv.y);
    ob[2] = f2bf((v[2] - mean) * inv * gv.z + bv.z);
    ob[3] = f2bf((v[3] - mean) * inv * gv.w + bv.w);
    *(u16x4*)&hb[(size_t)row * H + c] = ob;
}

// ---------------- Residual + LayerNorm (bf16 stream; sums NS stacked delta partials) ----------------
template<int NS>
__global__ void residual_ln_kernel(unsigned short* __restrict__ hb,
                                   const unsigned short* __restrict__ delta,
                                   const float* __restrict__ g,
                                   const float* __restrict__ bta) {
    const int row = blockIdx.x;
    const int t = threadIdx.x;     // 192
    const int c = t << 2;
    const size_t base = (size_t)row * H + c;
    const u16x4 hv4 = *(const u16x4*)&hb[base];
    float v[4] = {bf2f(hv4[0]), bf2f(hv4[1]), bf2f(hv4[2]), bf2f(hv4[3])};
#pragma unroll
    for (int sgm = 0; sgm < NS; ++sgm) {
        const u16x4 dv4 = *(const u16x4*)&delta[sgm * MH + base];
#pragma unroll
        for (int j = 0; j < 4; ++j) v[j] += bf2f(dv4[j]);
    }
    float s1 = v[0] + v[1] + v[2] + v[3];
    float s2 = v[0]*v[0] + v[1]*v[1] + v[2]*v[2] + v[3]*v[3];
#pragma unroll
    for (int o = 32; o; o >>= 1) { s1 += __shfl_xor(s1, o); s2 += __shfl_xor(s2, o); }
    __shared__ float ws[3][2];
    const int w = t >> 6, l = t & 63;
    if (l == 0) { ws[w][0] = s1; ws[w][1] = s2; }
    __syncthreads();
    const float S1 = ws[0][0] + ws[1][0] + ws[2][0];
    const float S2 = ws[0][1] + ws[1][1] + ws[2][1];
    const float mean = S1 * (1.0f / H);
    const float var = fmaxf(S2 * (1.0f / H) - mean * mean, 0.f);
    const float inv = rsqrtf(var + LN_EPS);
    const float4 gv = *(const float4*)&g[c];
    const float4 bv = *(const float4*)&bta[c];
    u16x4 ob;
    ob[0] = f2bf((v[0] - mean) * inv * gv.x + bv.x);
    ob[1] = f2bf((v[1] - mean) * inv * gv.y + bv.y);
    ob[2] = f2bf((v[2] - mean) * inv * gv.z + bv.z);
    ob[3] = f2bf((v[3] - mean) * inv * gv.w + bv.w);
    *(u16x4*)&hb[base] = ob;
}

#define LSTR 72

// ---------------- bf16 MFMA GEMM: C = A @ WT^T (+ bias on split 0) ----------------
// Tile (MR*32) x (NR*32), 4 waves (2x2). Reg-staged padded LDS, BK=64, 3 blocks/CU.
// K-split via blockIdx.z. XCD-aware swizzle over the (x,y) plane.
template<int ACT, int MR, int NR>
__global__ __launch_bounds__(256, 3)
void gemm_bf16(const unsigned short* __restrict__ A,
               const unsigned short* __restrict__ WT,
               const float* __restrict__ bias,
               unsigned short* __restrict__ Cb,
               int Ksub, int Kfull, int N, size_t splitStride) {
    __shared__ unsigned short lA[MR * 32 * LSTR];
    __shared__ unsigned short lB[NR * 32 * LSTR];
    const int tid = threadIdx.x;
    const int z = blockIdx.z;
    const int gx = gridDim.x;
    const int nb = gx * gridDim.y;
    int f = blockIdx.y * gx + blockIdx.x;
    f = (f & 7) * (nb >> 3) + (f >> 3);
    const int m0 = (f / gx) * (MR * 32), n0 = (f % gx) * (NR * 32);
    const int l = tid & 63, w = tid >> 6;
    const int wr = w >> 1, wc = w & 1;
    const int lr = l & 15, kg = l >> 4;

    const int srow = tid >> 3, scol = (tid & 7) << 3;
    const int kOff = z * Ksub;
    const unsigned short* gA = A + (size_t)(m0 + srow) * Kfull + kOff + scol;
    const unsigned short* gB = WT + (size_t)(n0 + srow) * Kfull + kOff + scol;

    f32x4 acc[MR][NR];
#pragma unroll
    for (int i = 0; i < MR; ++i)
#pragma unroll
        for (int j = 0; j < NR; ++j) acc[i][j] = (f32x4){0.f, 0.f, 0.f, 0.f};

    u16x8 ra[MR], rb[NR];
#pragma unroll
    for (int p = 0; p < MR; ++p) ra[p] = *(const u16x8*)(gA + (size_t)p * 32 * Kfull);
#pragma unroll
    for (int p = 0; p < NR; ++p) rb[p] = *(const u16x8*)(gB + (size_t)p * 32 * Kfull);

    for (int kt = 0; kt < Ksub; kt += 64) {
#pragma unroll
        for (int p = 0; p < MR; ++p)
            *(u16x8*)&lA[(srow + p * 32) * LSTR + scol] = ra[p];
#pragma unroll
        for (int p = 0; p < NR; ++p)
            *(u16x8*)&lB[(srow + p * 32) * LSTR + scol] = rb[p];
        __syncthreads();
        if (kt + 64 < Ksub) {
#pragma unroll
            for (int p = 0; p < MR; ++p) ra[p] = *(const u16x8*)(gA + (size_t)p * 32 * Kfull + kt + 64);
#pragma unroll
            for (int p = 0; p < NR; ++p) rb[p] = *(const u16x8*)(gB + (size_t)p * 32 * Kfull + kt + 64);
        }
#pragma unroll
        for (int ks = 0; ks < 2; ++ks) {
            bf16x8 af[MR], bfr[NR];
#pragma unroll
            for (int m = 0; m < MR; ++m)
                af[m] = *(const bf16x8*)&lA[(wr * (MR * 16) + (m << 4) + lr) * LSTR + ks * 32 + (kg << 3)];
#pragma unroll
            for (int n = 0; n < NR; ++n)
                bfr[n] = *(const bf16x8*)&lB[((wc * (NR * 16)) + (n << 4) + lr) * LSTR + ks * 32 + (kg << 3)];
#pragma unroll
            for (int m = 0; m < MR; ++m)
#pragma unroll
                for (int n = 0; n < NR; ++n)
                    acc[m][n] = __builtin_amdgcn_mfma_f32_16x16x32_bf16(af[m], bfr[n], acc[m][n], 0, 0, 0);
        }
        __syncthreads();
    }

    unsigned short* Cz = Cb + (size_t)z * splitStride;
    const int rbase = m0 + wr * (MR * 16) + (kg << 2);
    const int cbase = n0 + wc * (NR * 16) + lr;
#pragma unroll
    for (int m = 0; m < MR; ++m) {
#pragma unroll
        for (int n = 0; n < NR; ++n) {
            const int col = cbase + (n << 4);
            const float bv = (z == 0) ? bias[col] : 0.f;
#pragma unroll
            for (int j = 0; j < 4; ++j) {
                const int row = rbase + (m << 4) + j;
                float v = acc[m][n][j] + bv;
                if (ACT == 1) v = fast_gelu(v);
                Cz[(size_t)row * N + col] = f2bf(v);
            }
        }
    }
}

// ---------------- MFMA attention: block = (b, h, 128-q-half); V transposed in-LDS ----------------
__global__ __launch_bounds__(256, 2)
void attn_mfma(const unsigned short* __restrict__ qkv,
               unsigned short* __restrict__ ctxb) {
    __shared__ unsigned short Ks[256 * 72];
    __shared__ unsigned short Vt[64 * 264];
    __shared__ unsigned short Ps[4][16 * 72];

    // XCD swizzle: 384 blocks -> 48 contiguous logical blocks per XCD
    int f = blockIdx.x;
    f = (f & 7) * 48 + (f >> 3);
    const int half = f & 1;
    const int hh = (f >> 1) % NH;
    const int b = f / (2 * NH);
    const int t = threadIdx.x;
    const int l = t & 63, w = t >> 6;
    const int l15 = l & 15, g = l >> 4;

    {
        const int c0 = (t & 7) << 3;
        int r = t >> 3;
#pragma unroll
        for (int it = 0; it < 8; ++it, r += 32) {
            u16x8 kv = *(const u16x8*)&qkv[(size_t)(b * S + r) * QKVS + H + hh * 64 + c0];
            *(u16x8*)&Ks[r * 72 + c0] = kv;
        }
    }
    {
        const int d0 = (t & 7) << 3;
        int s = t >> 3;
#pragma unroll
        for (int it = 0; it < 8; ++it, s += 32) {
            u16x8 vv = *(const u16x8*)&qkv[(size_t)(b * S + s) * QKVS + 2 * H + hh * 64 + d0];
#pragma unroll
            for (int j = 0; j < 8; ++j) {
                int d = d0 + j;
                Vt[d * 264 + (s ^ (((d >> 3) & 7) << 3))] = vv[j];
            }
        }
    }
    __syncthreads();

    unsigned short* ps = Ps[w];
#pragma unroll
    for (int qi = 0; qi < 2; ++qi) {
        const int qrow = half * 128 + qi * 64 + w * 16 + l15;
        const unsigned short* qp = &qkv[(size_t)(b * S + qrow) * QKVS + hh * 64 + g * 8];
        bf16x8 aq0 = *(const bf16x8*)qp;
        bf16x8 aq1 = *(const bf16x8*)(qp + 32);

        f32x4 acc[16];
#pragma unroll
        for (int n = 0; n < 16; ++n) acc[n] = (f32x4){0.f, 0.f, 0.f, 0.f};
        __builtin_amdgcn_s_setprio(1);
#pragma unroll
        for (int n = 0; n < 16; ++n) {
            const unsigned short* kp = &Ks[(n * 16 + l15) * 72 + g * 8];
            bf16x8 b0 = *(const bf16x8*)kp;
            bf16x8 b1 = *(const bf16x8*)(kp + 32);
            acc[n] = __builtin_amdgcn_mfma_f32_16x16x32_bf16(aq0, b0, acc[n], 0, 0, 0);
            acc[n] = __builtin_amdgcn_mfma_f32_16x16x32_bf16(aq1, b1, acc[n], 0, 0, 0);
        }
        __builtin_amdgcn_s_setprio(0);

        float inv[4];
#pragma unroll
        for (int j = 0; j < 4; ++j) {
            float mx = acc[0][j];
#pragma unroll
            for (int n = 1; n < 16; ++n) mx = fmaxf(mx, acc[n][j]);
            mx = fmaxf(mx, __shfl_xor(mx, 1));
            mx = fmaxf(mx, __shfl_xor(mx, 2));
            mx = fmaxf(mx, __shfl_xor(mx, 4));
            mx = fmaxf(mx, __shfl_xor(mx, 8));
            float sum = 0.f;
#pragma unroll
            for (int n = 0; n < 16; ++n) {
                float e = exp2f((acc[n][j] - mx) * 0.18033688011112042f);
                acc[n][j] = e;
                sum += e;
            }
            sum += __shfl_xor(sum, 1);
            sum += __shfl_xor(sum, 2);
            sum += __shfl_xor(sum, 4);
            sum += __shfl_xor(sum, 8);
            inv[j] = 1.0f / sum;
        }

        f32x4 cacc[4];
#pragma unroll
        for (int nd = 0; nd < 4; ++nd) cacc[nd] = (f32x4){0.f, 0.f, 0.f, 0.f};
#pragma unroll
        for (int c = 0; c < 4; ++c) {
#pragma unroll
            for (int nl = 0; nl < 4; ++nl) {
                int n = c * 4 + nl;
#pragma unroll
                for (int j = 0; j < 4; ++j)
                    ps[(g * 4 + j) * 72 + nl * 16 + l15] = f2bf(acc[n][j]);
            }
            bf16x8 pa0 = *(const bf16x8*)&ps[l15 * 72 + g * 8];
            bf16x8 pa1 = *(const bf16x8*)&ps[l15 * 72 + 32 + g * 8];
            __builtin_amdgcn_s_setprio(1);
#pragma unroll
            for (int nd = 0; nd < 4; ++nd) {
                const int d = nd * 16 + l15;
                const int swz = ((d >> 3) & 7) << 3;
                const unsigned short* vp0 = &Vt[d * 264 + ((c * 64 + g * 8) ^ swz)];
                const unsigned short* vp1 = &Vt[d * 264 + ((c * 64 + 32 + g * 8) ^ swz)];
                bf16x8 v0 = *(const bf16x8*)vp0;
                bf16x8 v1 = *(const bf16x8*)vp1;
                cacc[nd] = __builtin_amdgcn_mfma_f32_16x16x32_bf16(pa0, v0, cacc[nd], 0, 0, 0);
                cacc[nd] = __builtin_amdgcn_mfma_f32_16x16x32_bf16(pa1, v1, cacc[nd], 0, 0, 0);
            }
            __builtin_amdgcn_s_setprio(0);
        }

#pragma unroll
        for (int nd = 0; nd < 4; ++nd)
#pragma unroll
            for (int j = 0; j < 4; ++j) {
                int qr = half * 128 + qi * 64 + w * 16 + g * 4 + j;
                ctxb[(size_t)(b * S + qr) * H + hh * 64 + nd * 16 + l15] = f2bf(cacc[nd][j] * inv[j]);
            }
    }
}

// ---------------- Classifier: one wave per row (bf16 h) ----------------
__global__ void clf_kernel(const unsigned short* __restrict__ hb,
                           const float* __restrict__ W,
                           const float* __restrict__ bias,
                           float* __restrict__ logits) {
    const int row = blockIdx.x * 4 + (threadIdx.x >> 6);
    const int l = threadIdx.x & 63;
    const unsigned short* hp = hb + (size_t)row * H;
    float acc[T] = {};
#pragma unroll
    for (int i = 0; i < 12; ++i) {
        const int k = l + (i << 6);
        const float x = bf2f(hp[k]);
        const float* wp = &W[k * T];
#pragma unroll
        for (int n = 0; n < T; ++n) acc[n] += x * wp[n];
    }
#pragma unroll
    for (int o = 32; o; o >>= 1)
#pragma unroll
        for (int n = 0; n < T; ++n) acc[n] += __shfl_xor(acc[n], o);
    if (l < T) logits[(size_t)row * T + l] = acc[l] + bias[l];
}

// ---------------- CRF chunk: 9x9 transfer-matrix product over 16 steps (log-semiring) ----------------
__global__ void crf_chunk_kernel(const float* __restrict__ logits,
                                 const int* __restrict__ target,
                                 const float* __restrict__ trans,
                                 float* __restrict__ Tc) {
    const int blk = blockIdx.x;
    const int b = blk >> 4, c = blk & 15;
    const int t = threadIdx.x;     // 128
    const int i = t / 9, j = t - i * 9;
    const bool act = t < 81;
    __shared__ float Tb[2][81];
    const float* lg = logits + (size_t)b * S * T;
    const int* tg = target + b * S;
    const float K2 = 1.44269504088896340736f;
    const float IK = 0.69314718055994530942f;

    float trc[T];
    if (act) {
#pragma unroll
        for (int k = 0; k < T; ++k) trc[k] = trans[k * T + j];
        Tb[0][t] = (i == j) ? 0.f : -1e30f;
    }
    __syncthreads();

    int p = 0;
    const int s0 = c * 16 + 1;
    const int s1 = (c == 15) ? S : (s0 + 16);
    for (int s = s0; s < s1; ++s) {
        if (tg[s] > -1) {
            if (act) {
                const float em = lg[s * T + j];
                float v[T];
#pragma unroll
                for (int k = 0; k < T; ++k) v[k] = Tb[p][i * 9 + k] + trc[k];
                float mx = fmaxf(v[0], v[1]);
                mx = fmaxf(mx, fmaxf(v[2], v[3]));
                mx = fmaxf(mx, fmaxf(v[4], v[5]));
                mx = fmaxf(mx, fmaxf(v[6], v[7]));
                mx = fmaxf(mx, v[8]);
                float sum = 0.f;
#pragma unroll
                for (int k = 0; k < T; ++k) sum += exp2f((v[k] - mx) * K2);
                Tb[p ^ 1][t] = mx + IK * log2f(sum) + em;
            }
            __syncthreads();
            p ^= 1;
        }
    }
    if (act) Tc[(size_t)blk * 81 + t] = Tb[p][t];
}

// ---------------- CRF final: numerator + chunk combine + denominator + mean, one block ----------------
__global__ __launch_bounds__(1024)
void crf_final_kernel(const float* __restrict__ logits,
                      const int* __restrict__ target,
                      const float* __restrict__ start,
                      const float* __restrict__ trans,
                      const float* __restrict__ endv,
                      const float* __restrict__ Tc,
                      float* __restrict__ out) {
    const int t = threadIdx.x;   // 1024 = 16 waves; wave = batch
    const int b = t >> 6, l = t & 63;
    const float* lg = logits + (size_t)b * S * T;
    const int* tg = target + b * S;
    const float K2 = 1.44269504088896340736f;
    const float IK = 0.69314718055994530942f;

    float pnum = 0.f; int pcnt = 0;
#pragma unroll
    for (int c = 0; c < 4; ++c) {
        const int s = 1 + l + (c << 6);
        if (s < S) {
            const int tcur = tg[s], tprev = tg[s - 1];
            const bool m = tcur > -1;
            const int tag = m ? tcur : 0;
            const int ptag = (tprev > -1) ? tprev : 0;
            if (m) { pnum += trans[ptag * T + tag] + lg[s * T + tag]; pcnt += 1; }
        }
    }
#pragma unroll
    for (int o = 32; o; o >>= 1) { pnum += __shfl_xor(pnum, o); pcnt += __shfl_xor(pcnt, o); }

    const int jj = (l < T) ? l : 0;
    float a = start[jj] + lg[jj];
    for (int c = 0; c < NCH; ++c) {
        const float* Tm = Tc + ((size_t)(b * NCH + c)) * 81;
        float v[T];
#pragma unroll
        for (int i2 = 0; i2 < T; ++i2) v[i2] = __shfl(a, i2) + Tm[i2 * 9 + jj];
        float mx = fmaxf(v[0], v[1]);
        mx = fmaxf(mx, fmaxf(v[2], v[3]));
        mx = fmaxf(mx, fmaxf(v[4], v[5]));
        mx = fmaxf(mx, fmaxf(v[6], v[7]));
        mx = fmaxf(mx, v[8]);
        float sum = 0.f;
#pragma unroll
        for (int k = 0; k < T; ++k) sum += exp2f((v[k] - mx) * K2);
        a = mx + IK * log2f(sum);
    }

    float val = (l < T) ? (a + endv[jj]) : -1e30f;
    float mx = val;
#pragma unroll
    for (int o = 8; o; o >>= 1) mx = fmaxf(mx, __shfl_xor(mx, o));
    float sm = (l < T) ? exp2f((val - mx) * K2) : 0.f;
#pragma unroll
    for (int o = 8; o; o >>= 1) sm += __shfl_xor(sm, o);
    const float denom = mx + IK * log2f(sm);

    __shared__ float part[16];
    if (l == 0) {
        const bool m0 = tg[0] > -1;
        const int tag0 = m0 ? tg[0] : 0;
        const int cnt = pcnt + (m0 ? 1 : 0);
        int lastIdx = cnt - 1; if (lastIdx < 0) lastIdx = 0;
        const int lt = tg[lastIdx];
        const int lastTag = (lt > -1) ? lt : 0;
        const float num = start[tag0] + lg[tag0] + pnum + endv[lastTag];
        part[b] = num - denom;
    }
    __syncthreads();
    if (t == 0) {
        float s = 0.f;
#pragma unroll
        for (int i = 0; i < 16; ++i) s += part[i];
        out[0] = -s * (1.0f / 16.0f);
    }
}

// ---------------- Host launch ----------------
extern "C" void kernel_launch(void* const* d_in, const int* in_sizes, int n_in,
                              void* d_out, int out_size, void* d_ws, size_t ws_size,
                              hipStream_t stream) {
    const int*   x        = (const int*)d_in[0];
    const int*   target   = (const int*)d_in[1];
    const float* word_emb = (const float*)d_in[2];
    const float* pos_emb  = (const float*)d_in[3];
    const float* type_emb = (const float*)d_in[4];
    const float* emb_ln_g = (const float*)d_in[5];
    const float* emb_ln_b = (const float*)d_in[6];
    const float* Wq = (const float*)d_in[7];
    const float* bq = (const float*)d_in[8];
    const float* Wk = (const float*)d_in[9];
    const float* bk = (const float*)d_in[10];
    const float* Wv = (const float*)d_in[11];
    const float* bv = (const float*)d_in[12];
    const float* Wo = (const float*)d_in[13];
    const float* bo = (const float*)d_in[14];
    const float* ln1_g = (const float*)d_in[15];
    const float* ln1_b = (const float*)d_in[16];
    const float* W1 = (const float*)d_in[17];
    const float* b1 = (const float*)d_in[18];
    const float* W2 = (const float*)d_in[19];
    const float* b2 = (const float*)d_in[20];
    const float* ln2_g = (const float*)d_in[21];
    const float* ln2_b = (const float*)d_in[22];
    const float* clf_W = (const float*)d_in[23];
    const float* clf_b = (const float*)d_in[24];
    const float* crf_start = (const float*)d_in[25];
    const float* crf_trans = (const float*)d_in[26];
    const float* crf_end   = (const float*)d_in[27];

    char* ws = (char*)d_ws;
    size_t off = 0;
    auto alloc = [&](size_t bytes) { void* p = ws + off; off += (bytes + 255) & ~255ull; return p; };

    unsigned short* wqkvT = (unsigned short*)alloc((size_t)L * 3 * H * H * 2);
    unsigned short* woT   = (unsigned short*)alloc((size_t)L * H * H * 2);
    unsigned short* w1T   = (unsigned short*)alloc((size_t)L * H * DFF * 2);
    unsigned short* w2T   = (unsigned short*)alloc((size_t)L * H * DFF * 2);
    float*          bcat  = (float*)alloc((size_t)L * QKVS * 4);
    unsigned short* hb    = (unsigned short*)alloc(MH * 2);
    unsigned short* qkvb  = (unsigned short*)alloc((size_t)M * QKVS * 2);
    unsigned short* ctxb  = (unsigned short*)alloc(MH * 2);
    unsigned short* gob   = (unsigned short*)alloc(4 * MH * 2);   // K-split partials
    unsigned short* ffb   = (unsigned short*)alloc((size_t)M * DFF * 2);
    float*          logits = (float*)alloc((size_t)M * T * 4);
    float*          Tcbuf  = (float*)alloc((size_t)B * NCH * 81 * 4);

    dim3 tb(32, 8);
    convT4_kernel<<<dim3(H / 32, H / 32, 4 * L), tb, 0, stream>>>(Wq, Wk, Wv, Wo, wqkvT, woT);
    convTFF_kernel<<<dim3(DFF / 32, H / 32, 2 * L), tb, 0, stream>>>(W1, W2, w1T, w2T);
    biascat_kernel<<<(L * QKVS + 255) / 256, 256, 0, stream>>>(bq, bk, bv, bcat);

    embed_ln_kernel<<<M, 192, 0, stream>>>(x, word_emb, pos_emb, type_emb, emb_ln_g, emb_ln_b, hb);

    const dim3 gQKV(QKVS / 96, M / 128, 1);   // 24 x 32      (MR=4, NR=3 -> 768 blocks = 3/CU)
    const dim3 gFF1(DFF / 128, M / 128, 1);   // 24 x 32      (MR=4, NR=4 -> 768 blocks)
    const dim3 gWo (H / 128, M / 64, 2);      // 6 x 64 x 2   (MR=2, NR=4, K-split 2 -> 768)
    const dim3 gFF2(H / 128, M / 64, 2);      // 6 x 64 x 2   (MR=2, NR=4, K-split 2 -> 768, Ksub=1536)

    for (int l = 0; l < L; ++l) {
        gemm_bf16<0, 4, 3><<<gQKV, 256, 0, stream>>>(hb, wqkvT + (size_t)l * 3 * H * H, bcat + l * QKVS,
                                                     qkvb, H, H, QKVS, 0);
        attn_mfma<<<B * NH * 2, 256, 0, stream>>>(qkvb, ctxb);
        gemm_bf16<0, 2, 4><<<gWo, 256, 0, stream>>>(ctxb, woT + (size_t)l * H * H, bo + l * H,
                                                    gob, H / 2, H, H, MH);
        residual_ln_kernel<2><<<M, 192, 0, stream>>>(hb, gob, ln1_g + l * H, ln1_b + l * H);
        gemm_bf16<1, 4, 4><<<gFF1, 256, 0, stream>>>(hb, w1T + (size_t)l * H * DFF, b1 + l * DFF,
                                                     ffb, H, H, DFF, 0);
        gemm_bf16<0, 2, 4><<<gFF2, 256, 0, stream>>>(ffb, w2T + (size_t)l * H * DFF, b2 + l * H,
                                                     gob, DFF / 2, DFF, H, MH);
        residual_ln_kernel<2><<<M, 192, 0, stream>>>(hb, gob, ln2_g + l * H, ln2_b + l * H);
    }

    clf_kernel<<<M / 4, 256, 0, stream>>>(hb, clf_W, clf_b, logits);
    crf_chunk_kernel<<<B * NCH, 128, 0, stream>>>(logits, target, crf_trans, Tcbuf);
    crf_final_kernel<<<1, 1024, 0, stream>>>(logits, target, crf_start, crf_trans, crf_end, Tcbuf, (float*)d_out);
}